// Round 16
// baseline (143.256 us; speedup 1.0000x reference)
//
#include <hip/hip_runtime.h>
#include <stdint.h>

#define N_Q    4096
#define D_K    512
#define D_OUT  16384
#define NCLUST 256

// GEMM: 256x128 tile, BK=32, 4 waves (2M x 2N), per-wave 128x64 (acc 8x4).
// Ring-3 slots of 24 KB = 72 KB -> 2 WG/CU, counted WAIT_BAR(6), T2 swizzle,
// setprio, XCD panel mapping, LDS-transposed full-line epilogue.
// Round-16 A/B: plain write-back stores instead of nontemporal (NT holds
// write credits to HBM-commit ~600-900cy on the wave's critical path; plain
// commits at L2 ~200cy and drains async; full-line writes -> no allocate
// fetch). Everything else is round-15 verbatim (133.0us, tied best).
#define BM 256
#define BN 128
#define BK 32
#define NT (D_K / BK)   // 16 K-tiles
#define SCP 132         // sC row stride in floats (non-pow2: conflict-free)

typedef __attribute__((ext_vector_type(4))) float f32x4;
typedef __attribute__((ext_vector_type(8))) short bf16x8;

__device__ __forceinline__ uint32_t f2bf(float f) {
  uint32_t u = __float_as_uint(f);
  u += 0x7FFFu + ((u >> 16) & 1u);
  return u >> 16;
}

#define GLOAD_LDS16(g, l)                                         \
  __builtin_amdgcn_global_load_lds(                               \
      (const __attribute__((address_space(1))) void*)(g),         \
      (__attribute__((address_space(3))) void*)(l), 16, 0, 0)

#define WAIT_BAR(N) asm volatile("s_waitcnt vmcnt(" #N ")\n\ts_barrier" ::: "memory")
#define LBAR() asm volatile("s_waitcnt lgkmcnt(0)\n\ts_barrier" ::: "memory")

// merged: W f32->bf16 convert (blocks 0..4095) + centroid transpose (4096..4223)
__global__ __launch_bounds__(256) void prep_kernel(const float* __restrict__ weight,
                                                   ushort* __restrict__ W_bf,
                                                   const float* __restrict__ cent,
                                                   float4* __restrict__ centT4,
                                                   float* __restrict__ cmask) {
  int b = blockIdx.x;
  if (b < (D_OUT * D_K / 8) / 256) {
    int i = b * 256 + threadIdx.x;
    const float4* s = reinterpret_cast<const float4*>(weight) + (size_t)i * 2;
    float4 v0 = s[0], v1 = s[1];
    uint4 o;
    o.x = f2bf(v0.x) | (f2bf(v0.y) << 16);
    o.y = f2bf(v0.z) | (f2bf(v0.w) << 16);
    o.z = f2bf(v1.x) | (f2bf(v1.y) << 16);
    o.w = f2bf(v1.z) | (f2bf(v1.w) << 16);
    reinterpret_cast<uint4*>(W_bf)[i] = o;
  } else {
    int bb = b - (D_OUT * D_K / 8) / 256;
    if (bb == 0) cmask[threadIdx.x] = 0.0f;
    int idx = bb * 256 + threadIdx.x;
    int k4 = idx & 127, c = idx >> 7;
    float4 v = *reinterpret_cast<const float4*>(&cent[(size_t)c * D_K + k4 * 4]);
    centT4[(size_t)k4 * NCLUST + c] = v;
  }
}

// 8 queries/block; thread t owns centroid t; fused A f32->bf16 convert.
// f32 routing math throughout (threshold booleans must not flip).
__global__ __launch_bounds__(256) void routing_kernel(const float* __restrict__ input,
                                                      const float4* __restrict__ centT4,
                                                      float* __restrict__ qmask,
                                                      float* __restrict__ cmask,
                                                      ushort* __restrict__ A_bf) {
  __shared__ float lgs[8][NCLUST];
  int c = threadIdx.x;
  int q0 = blockIdx.x * 8;
  const float* __restrict__ inp = input + (size_t)q0 * D_K;

  {
    const float4* s4 = reinterpret_cast<const float4*>(inp) + c * 4;
    float4 x0 = s4[0], x1 = s4[1], x2 = s4[2], x3 = s4[3];
    uint4 o0, o1;
    o0.x = f2bf(x0.x) | (f2bf(x0.y) << 16);
    o0.y = f2bf(x0.z) | (f2bf(x0.w) << 16);
    o0.z = f2bf(x1.x) | (f2bf(x1.y) << 16);
    o0.w = f2bf(x1.z) | (f2bf(x1.w) << 16);
    o1.x = f2bf(x2.x) | (f2bf(x2.y) << 16);
    o1.y = f2bf(x2.z) | (f2bf(x2.w) << 16);
    o1.z = f2bf(x3.x) | (f2bf(x3.y) << 16);
    o1.w = f2bf(x3.z) | (f2bf(x3.w) << 16);
    uint4* dst = reinterpret_cast<uint4*>(A_bf + (size_t)q0 * D_K);
    dst[c * 2] = o0;
    dst[c * 2 + 1] = o1;
  }

  float acc[8] = {0, 0, 0, 0, 0, 0, 0, 0};
  for (int k4 = 0; k4 < D_K / 4; ++k4) {
    float4 v = centT4[(size_t)k4 * NCLUST + c];
#pragma unroll
    for (int q = 0; q < 8; ++q) {
      float4 r = *reinterpret_cast<const float4*>(&inp[q * D_K + k4 * 4]);  // uniform addr
      acc[q] += v.x * r.x + v.y * r.y + v.z * r.z + v.w * r.w;
    }
  }
#pragma unroll
  for (int q = 0; q < 8; ++q) lgs[q][c] = acc[q] * 10.0f;  // /TEMPERATURE
  __syncthreads();

  int wave = c >> 6, lane = c & 63;
#pragma unroll
  for (int qq = 0; qq < 2; ++qq) {
    int q = wave * 2 + qq;
    float4 lv = *reinterpret_cast<const float4*>(&lgs[q][lane * 4]);
    float m = fmaxf(fmaxf(lv.x, lv.y), fmaxf(lv.z, lv.w));
#pragma unroll
    for (int off = 32; off > 0; off >>= 1) m = fmaxf(m, __shfl_xor(m, off));
    float e0 = expf(lv.x - m), e1 = expf(lv.y - m), e2 = expf(lv.z - m), e3 = expf(lv.w - m);
    float s = e0 + e1 + e2 + e3;
#pragma unroll
    for (int off = 32; off > 0; off >>= 1) s += __shfl_xor(s, off);
    float thr = 0.01f * s;
    bool a0 = e0 > thr, a1 = e1 > thr, a2 = e2 > thr, a3 = e3 > thr;
    if (a0) cmask[lane * 4 + 0] = 1.0f;  // benign races: all writers store 1.0
    if (a1) cmask[lane * 4 + 1] = 1.0f;
    if (a2) cmask[lane * 4 + 2] = 1.0f;
    if (a3) cmask[lane * 4 + 3] = 1.0f;
    unsigned long long any = __ballot(a0 | a1 | a2 | a3);
    if (lane == 0) qmask[q0 + q] = any ? 1.0f : 0.0f;
  }
}

__global__ __launch_bounds__(256, 2) void gemm_masked_kernel(
    const ushort* __restrict__ A, const ushort* __restrict__ W,
    const float* __restrict__ bias, const int* __restrict__ assign,
    const float* __restrict__ qmask, const float* __restrict__ cmask,
    float* __restrict__ C) {
  // LDS 72 KB: 3 slots of 24 KB = {A 16 KB (4 x 4KB row-groups) | B 8 KB}.
  // Epilogue reuses front 33.8 KB as sC[64][SCP]. 2 WG/CU.
  __shared__ __align__(16) char smem[73728];

  int tid = threadIdx.x;
  int wave = tid >> 6, lane = tid & 63;

  // XCD mapping: xcd = bid&7 owns ntiles [16x,16x+16); ntile fast within XCD
  // (2 MB W-set L2-resident). 2048 = 8*16*16 -> bijective.
  int bid = blockIdx.x;
  int idx = bid >> 3;                         // 0..255
  int ntile = (bid & 7) * 16 + (idx & 15);    // 0..127
  int mtile = idx >> 4;                       // 0..15
  int m0 = mtile * BM, n0 = ntile * BN;

  int wr = wave >> 1, wc = wave & 1;  // 2x2 wave grid; per-wave C: 128x64

  // staging: LDS (row,kg) <- global (row, kg ^ ((row>>1)&3)); linear LDS dest,
  // pre-swizzled per-lane source (rule #21). ((64p+r)>>1)&3 == ((r>>1)&3) ✓.
  int srow = tid >> 2, kg = tid & 3;
  int ks = (kg ^ ((srow >> 1) & 3)) * 8;
  const ushort* srcA = A + (size_t)(m0 + srow) * D_K + ks;   // + 64p rows, p=0..3
  const ushort* srcB = W + (size_t)(n0 + srow) * D_K + ks;   // + 64p rows, p=0..1
  int wo = wave << 10;  // wave's 1 KB chunk within each 4 KB row-group

#define STAGE(j) do {                                                    \
    char* sl_ = smem + ((j) % 3) * 24576 + wo;                           \
    GLOAD_LDS16(srcA + (j) * BK, sl_);                                   \
    GLOAD_LDS16(srcA + (size_t)64 * D_K + (j) * BK, sl_ + 4096);         \
    GLOAD_LDS16(srcA + (size_t)128 * D_K + (j) * BK, sl_ + 8192);        \
    GLOAD_LDS16(srcA + (size_t)192 * D_K + (j) * BK, sl_ + 12288);       \
    GLOAD_LDS16(srcB + (j) * BK, sl_ + 16384);                           \
    GLOAD_LDS16(srcB + (size_t)64 * D_K + (j) * BK, sl_ + 20480);        \
  } while (0)

  // fragment read indices (swizzled), ushort units within a slot.
  int kg0 = lane >> 4, l15 = lane & 15, lr = lane >> 4;
  int aIdx[8], bIdx[4];
#pragma unroll
  for (int m = 0; m < 8; ++m) {
    int r = wr * 128 + m * 16 + l15;
    aIdx[m] = r * 32 + ((kg0 ^ ((r >> 1) & 3)) << 3);
  }
#pragma unroll
  for (int n = 0; n < 4; ++n) {
    int r = wc * 64 + n * 16 + l15;
    bIdx[n] = 8192 + r * 32 + ((kg0 ^ ((r >> 1) & 3)) << 3);  // B at +16 KB
  }

  f32x4 acc[8][4] = {};

  STAGE(0);
  STAGE(1);

#pragma unroll
  for (int t = 0; t < NT; ++t) {
    // loop top: tile t's 6 loads are oldest (12 outstanding with t+1's 6);
    // WAIT_BAR(6) retires exactly tile t, t+1 stays in flight.
    if (t < NT - 1) { WAIT_BAR(6); } else { WAIT_BAR(0); }

    const ushort* sl = (const ushort*)(smem + (t % 3) * 24576);
    bf16x8 af[8], bf[4];
#pragma unroll
    for (int n = 0; n < 4; ++n) bf[n] = *reinterpret_cast<const bf16x8*>(&sl[bIdx[n]]);
#pragma unroll
    for (int m = 0; m < 8; ++m) af[m] = *reinterpret_cast<const bf16x8*>(&sl[aIdx[m]]);
    if (t + 2 < NT) STAGE(t + 2);  // slot (t+2)%3 == (t-1)%3: reads retired pre-barrier

    __builtin_amdgcn_s_setprio(1);
#pragma unroll
    for (int m = 0; m < 8; ++m)
#pragma unroll
      for (int n = 0; n < 4; ++n)
        acc[m][n] = __builtin_amdgcn_mfma_f32_16x16x32_bf16(af[m], bf[n], acc[m][n], 0, 0, 0);
    __builtin_amdgcn_s_setprio(0);
    // closing barrier is next iteration's WAIT_BAR (or loop exit)
  }
#undef STAGE

  LBAR();  // all slot ds_reads retired; smem reusable as sC

  // LDS-transposed epilogue: 4 super-chunks of 64 rows x 128 cols via
  // sC[64][SCP]; full-line PLAIN stores (write-back L2; lines fully covered
  // -> no allocate-fetch; drain to HBM is async, off the wave critical path).
  float* sC = reinterpret_cast<float*>(smem);
  float bj[4], rm[4];
#pragma unroll
  for (int n = 0; n < 4; ++n) {
    int col = n0 + wc * 64 + n * 16 + l15;
    bj[n] = bias[col];
    rm[n] = cmask[assign[col]];
  }
#pragma unroll
  for (int s = 0; s < 4; ++s) {
#pragma unroll
    for (int e = 0; e < 2; ++e) {
      int m = 2 * s + e;
      float4 qm = *reinterpret_cast<const float4*>(&qmask[m0 + wr * 128 + m * 16 + lr * 4]);
      int rl = wr * 32 + e * 16 + lr * 4;  // sC local row
#pragma unroll
      for (int n = 0; n < 4; ++n) {
        int cc = wc * 64 + n * 16 + l15;
        sC[(rl + 0) * SCP + cc] = (acc[m][n][0] + bj[n]) * qm.x * rm[n];
        sC[(rl + 1) * SCP + cc] = (acc[m][n][1] + bj[n]) * qm.y * rm[n];
        sC[(rl + 2) * SCP + cc] = (acc[m][n][2] + bj[n]) * qm.z * rm[n];
        sC[(rl + 3) * SCP + cc] = (acc[m][n][3] + bj[n]) * qm.w * rm[n];
      }
    }
    LBAR();
    f32x4 v[8];
#pragma unroll
    for (int i = 0; i < 8; ++i) {
      int rl = wave * 16 + i * 2 + (lane >> 5);
      v[i] = *reinterpret_cast<const f32x4*>(&sC[rl * SCP + (lane & 31) * 4]);
    }
    LBAR();
#pragma unroll
    for (int i = 0; i < 8; ++i) {
      int rl = wave * 16 + i * 2 + (lane >> 5);
      int grow = m0 + (rl >> 5) * 128 + s * 32 + ((rl >> 4) & 1) * 16 + (rl & 15);
      *reinterpret_cast<f32x4*>(&C[(size_t)grow * D_OUT + n0 + (lane & 31) * 4]) = v[i];
    }
  }
}

extern "C" void kernel_launch(void* const* d_in, const int* in_sizes, int n_in,
                              void* d_out, int out_size, void* d_ws, size_t ws_size,
                              hipStream_t stream) {
  const float* input     = (const float*)d_in[0];
  const float* weight    = (const float*)d_in[1];
  const float* bias      = (const float*)d_in[2];
  const float* centroids = (const float*)d_in[3];
  const int*   assign    = (const int*)d_in[4];
  float* out = (float*)d_out;

  // ws layout (bytes):
  //   A_bf16 : 0          (4 MiB)
  //   W_bf16 : 4,194,304  (16 MiB)
  //   qmask  : 20,971,520 (16 KB)
  //   cmask  : 20,987,904 (1 KB)
  //   centT4 : 21,000,192 (512 KB)
  char* ws = (char*)d_ws;
  ushort* A_bf   = (ushort*)ws;
  ushort* W_bf   = (ushort*)(ws + 4194304);
  float*  qmask  = (float*)(ws + 20971520);
  float*  cmask  = (float*)(ws + 20987904);
  float4* centT4 = (float4*)(ws + 21000192);

  prep_kernel<<<4224, 256, 0, stream>>>(weight, W_bf, centroids, centT4, cmask);
  routing_kernel<<<N_Q / 8, 256, 0, stream>>>(input, centT4, qmask, cmask, A_bf);
  gemm_masked_kernel<<<(N_Q / BM) * (D_OUT / BN), 256, 0, stream>>>(
      A_bf, W_bf, bias, assign, qmask, cmask, out);
}